// Round 16
// baseline (802.014 us; speedup 1.0000x reference)
//
#include <hip/hip_runtime.h>

#define HID 128
#define BK_SHIFT 9            // 512 nodes per bucket
#define BK_NODES 512
#define BKCAP 10240           // padded slots per bucket (mean 8192, sigma ~90)
#define EDGES_PER_BLKA 8192
#define NSLAB 8               // 8 column-slabs of 16 cols; slab = 3.2MB (L2-resident)

typedef _Float16 half_t;
typedef __attribute__((ext_vector_type(8))) _Float16 half8;
typedef __attribute__((ext_vector_type(4))) _Float16 half4;
typedef __attribute__((ext_vector_type(4))) float f32x4;

// Slab-tiled feature layout: T[slab][(N+1) rows][16 cols] halfs.
// addr(slab,row,colin) = slab*(N+1)*16 + row*16 + colin. Row N = zero row.

// ---------------------------------------------------------------- fused setup: embed | packW x5 | init
__global__ __launch_bounds__(256) void k_setup(const float* __restrict__ pos,
                                               const int* __restrict__ an,
                                               const float* __restrict__ Win,
                                               const float* __restrict__ bin,
                                               half_t* __restrict__ h0,
                                               const float* __restrict__ w0,
                                               const float* __restrict__ w1,
                                               const float* __restrict__ w2,
                                               const float* __restrict__ w3,
                                               const float* __restrict__ w4,
                                               half_t* __restrict__ o0,
                                               half_t* __restrict__ o1,
                                               half_t* __restrict__ o2,
                                               half_t* __restrict__ o3,
                                               half_t* __restrict__ o4,
                                               int* __restrict__ bcur,
                                               float* __restrict__ outmean,
                                               half_t* __restrict__ h1,
                                               int n, int gEmbed) {
  size_t np1s = (size_t)(n + 1) * 16;
  int bid = blockIdx.x;
  if (bid < gEmbed) {
    int t = bid * 256 + threadIdx.x;
    int i = t >> 5, cg = t & 31;
    if (i >= n) return;
    int j0 = cg << 2;
    float z  = (float)an[i] / 10.0f;
    float px = pos[3 * i + 0], py = pos[3 * i + 1], pz = pos[3 * i + 2];
    float4 ww0 = *(const float4*)&Win[0 * HID + j0];
    float4 ww1 = *(const float4*)&Win[1 * HID + j0];
    float4 ww2 = *(const float4*)&Win[2 * HID + j0];
    float4 ww3 = *(const float4*)&Win[3 * HID + j0];
    float4 b   = *(const float4*)&bin[j0];
    float4 o;
    o.x = fmaxf(fmaf(z, ww0.x, fmaf(px, ww1.x, fmaf(py, ww2.x, fmaf(pz, ww3.x, b.x)))), 0.f);
    o.y = fmaxf(fmaf(z, ww0.y, fmaf(px, ww1.y, fmaf(py, ww2.y, fmaf(pz, ww3.y, b.y)))), 0.f);
    o.z = fmaxf(fmaf(z, ww0.z, fmaf(px, ww1.z, fmaf(py, ww2.z, fmaf(pz, ww3.z, b.z)))), 0.f);
    o.w = fmaxf(fmaf(z, ww0.w, fmaf(px, ww1.w, fmaf(py, ww2.w, fmaf(pz, ww3.w, b.w)))), 0.f);
    half4 ph;
    ph.x = (half_t)o.x; ph.y = (half_t)o.y; ph.z = (half_t)o.z; ph.w = (half_t)o.w;
    *(half4*)&h0[(size_t)(j0 >> 4) * np1s + (size_t)i * 16 + (j0 & 15)] = ph;
  } else if (bid < gEmbed + 40) {
    int pb = bid - gEmbed;
    int m = pb >> 3;
    const float* W = (m == 0) ? w0 : (m == 1) ? w1 : (m == 2) ? w2 : (m == 3) ? w3 : w4;
    half_t* out = (m == 0) ? o0 : (m == 1) ? o1 : (m == 2) ? o2 : (m == 3) ? o3 : o4;
    int tid = (pb & 7) * 256 + threadIdx.x;   // 0..2047
    int lane = tid & 63;
    int frag = tid >> 6;                      // 0..31
    int ks = frag >> 3, nt = frag & 7;
    int k0 = ks * 32 + ((lane >> 4) << 3);
    int col = nt * 16 + (lane & 15);
    half8 v;
#pragma unroll
    for (int i = 0; i < 8; ++i) v[i] = (half_t)W[(k0 + i) * HID + col];
    *(half8*)&out[(size_t)tid * 8] = v;
  } else {
    int i = threadIdx.x;
    bcur[i] = i * BKCAP;
    if (i < HID) outmean[i] = 0.f;
    if (i < HID) {
      // zero row (row n) for each of the 8 slabs of H0 and H1
      int slab = i >> 4, colin = i & 15;
      h0[(size_t)slab * np1s + (size_t)n * 16 + colin] = (half_t)0.f;
      h1[(size_t)slab * np1s + (size_t)n * 16 + colin] = (half_t)0.f;
    }
  }
}

// ---------------------------------------------------------------- pass A: bin edges into padded dst-buckets
__global__ __launch_bounds__(1024) void k_bucketA(const int* __restrict__ src,
                                                  const int* __restrict__ dst,
                                                  int* __restrict__ bcur,
                                                  unsigned* __restrict__ ebuf,
                                                  int e) {
  __shared__ int hist[256];
  __shared__ int resv[256];
  int t = threadIdx.x;
  if (t < 256) hist[t] = 0;
  __syncthreads();
  int base = blockIdx.x * EDGES_PER_BLKA + t * 8;
  int myb[8], myr[8];
  unsigned mypk[8];
  if (base + 8 <= e) {
    int4 sa = *(const int4*)&src[base];
    int4 sb = *(const int4*)&src[base + 4];
    int4 da = *(const int4*)&dst[base];
    int4 db = *(const int4*)&dst[base + 4];
    int ss[8] = {sa.x, sa.y, sa.z, sa.w, sb.x, sb.y, sb.z, sb.w};
    int dd[8] = {da.x, da.y, da.z, da.w, db.x, db.y, db.z, db.w};
#pragma unroll
    for (int i = 0; i < 8; ++i) {
      int b = dd[i] >> BK_SHIFT;
      myb[i] = b;
      myr[i] = atomicAdd(&hist[b], 1);
      mypk[i] = ((unsigned)ss[i] << BK_SHIFT) | (unsigned)(dd[i] & (BK_NODES - 1));
    }
  } else {
#pragma unroll
    for (int i = 0; i < 8; ++i) {
      int idx = base + i;
      if (idx < e) {
        int d = dst[idx];
        int s = src[idx];
        int b = d >> BK_SHIFT;
        myb[i] = b;
        myr[i] = atomicAdd(&hist[b], 1);
        mypk[i] = ((unsigned)s << BK_SHIFT) | (unsigned)(d & (BK_NODES - 1));
      } else {
        myb[i] = -1;
      }
    }
  }
  __syncthreads();
  if (t < 256) resv[t] = (hist[t] > 0) ? atomicAdd(&bcur[t], hist[t]) : 0;
  __syncthreads();
#pragma unroll
  for (int i = 0; i < 8; ++i) {
    if (myb[i] >= 0) ebuf[resv[myb[i]] + myr[i]] = mypk[i];
  }
}

// ---------------------------------------------------------------- pass B: per bucket (512 threads): LDS hist -> scan -> offs + csr
__global__ __launch_bounds__(512) void k_bucketB(const unsigned* __restrict__ ebuf,
                                                 const int* __restrict__ bkend,
                                                 int* __restrict__ offs,
                                                 int* __restrict__ offsE,
                                                 int* __restrict__ csr, int n) {
  __shared__ int hist[BK_NODES];
  __shared__ int red[BK_NODES];
  int b = blockIdx.x;
  int n0 = b << BK_SHIFT;
  int t = threadIdx.x;
  int ebeg = b * BKCAP, eend = bkend[b];
  hist[t] = 0;
  __syncthreads();
  for (int idx = ebeg + t * 4; idx < eend; idx += 2048) {
    if (idx + 4 <= eend) {
      uint4 pk = *(const uint4*)&ebuf[idx];
      atomicAdd(&hist[pk.x & (BK_NODES - 1)], 1);
      atomicAdd(&hist[pk.y & (BK_NODES - 1)], 1);
      atomicAdd(&hist[pk.z & (BK_NODES - 1)], 1);
      atomicAdd(&hist[pk.w & (BK_NODES - 1)], 1);
    } else {
      for (int k = 0; k < 4; ++k) {
        int id2 = idx + k;
        if (id2 < eend) atomicAdd(&hist[ebuf[id2] & (BK_NODES - 1)], 1);
      }
    }
  }
  __syncthreads();
  int h0 = hist[t];
  red[t] = h0;
  __syncthreads();
  for (int d = 1; d < 512; d <<= 1) {
    int u = (t >= d) ? red[t - d] : 0;
    __syncthreads();
    red[t] += u;
    __syncthreads();
  }
  int base0 = ebeg + (red[t] - h0);   // exclusive
  int g = n0 + t;
  if (g < n) { offs[g] = base0; offsE[g] = base0 + h0; }
  __syncthreads();
  hist[t] = base0;
  __syncthreads();
  for (int idx = ebeg + t * 4; idx < eend; idx += 2048) {
    if (idx + 4 <= eend) {
      uint4 pk = *(const uint4*)&ebuf[idx];
      csr[atomicAdd(&hist[pk.x & (BK_NODES - 1)], 1)] = (int)(pk.x >> BK_SHIFT);
      csr[atomicAdd(&hist[pk.y & (BK_NODES - 1)], 1)] = (int)(pk.y >> BK_SHIFT);
      csr[atomicAdd(&hist[pk.z & (BK_NODES - 1)], 1)] = (int)(pk.z >> BK_SHIFT);
      csr[atomicAdd(&hist[pk.w & (BK_NODES - 1)], 1)] = (int)(pk.w >> BK_SHIFT);
    } else {
      for (int k = 0; k < 4; ++k) {
        int id2 = idx + k;
        if (id2 < eend) {
          unsigned pk = ebuf[id2];
          csr[atomicAdd(&hist[pk & (BK_NODES - 1)], 1)] = (int)(pk >> BK_SHIFT);
        }
      }
    }
  }
}

// ---------------------------------------------------------------- sliced mean aggregation: 8 slice-passes, slice-major.
// Per pass the active slab (3.2MB) is L2-resident on every XCD. Wave = 1 node:
// es = lane>>1 (32 edge slots in flight), cs = lane&1 (two 16B halves of the 32B slab row).
__global__ __launch_bounds__(256) void k_aggmean_sl(const half_t* __restrict__ h,
                                                    const int* __restrict__ csr,
                                                    const int* __restrict__ offs,
                                                    const int* __restrict__ offsE,
                                                    half_t* __restrict__ out,
                                                    int n, int gNode) {
  int bid = blockIdx.x;
  int slice = bid / gNode;              // slice-major: blocks of one slice run together
  int nblk = bid - slice * gNode;
  int wid = threadIdx.x >> 6;
  int lane = threadIdx.x & 63;
  int w = nblk * 4 + wid;
  if (w >= n) return;
  int es = lane >> 1, cs = lane & 1;
  size_t slab = (size_t)slice * (size_t)(n + 1) * 16;
  const half_t* hs = h + slab;
  int beg = offs[w], end = offsE[w];
  float acc[8];
#pragma unroll
  for (int j = 0; j < 8; ++j) acc[j] = 0.f;
  int last = end - 1;
  for (int e = beg; e < end; e += 32) {
    int idx = e + es;
    int cidx = idx <= last ? idx : last;
    int sr = csr[cidx];
    int row = (idx <= last) ? sr : n;    // junk -> zero row
    half8 v = *(const half8*)&hs[(size_t)row * 16 + cs * 8];
#pragma unroll
    for (int j = 0; j < 8; ++j) acc[j] += (float)v[j];
  }
  // reduce over the 32 edge slots (bits 1..5 of lane)
#pragma unroll
  for (int j = 0; j < 8; ++j) {
    acc[j] += __shfl_xor(acc[j], 2, 64);
    acc[j] += __shfl_xor(acc[j], 4, 64);
    acc[j] += __shfl_xor(acc[j], 8, 64);
    acc[j] += __shfl_xor(acc[j], 16, 64);
    acc[j] += __shfl_xor(acc[j], 32, 64);
  }
  if (es == 0) {
    int c = end - beg;
    float inv = (c > 0) ? 1.0f / (float)c : 0.0f;
    half8 o;
#pragma unroll
    for (int j = 0; j < 8; ++j) o[j] = (half_t)(acc[j] * inv);
    *(half8*)&out[slab + (size_t)w * 16 + cs * 8] = o;
  }
}

// ---------------------------------------------------------------- MFMA SAGE (conv1): out = relu(ha@Wl + hs@Wr + b)
// ha/hs in slab-tiled layout; out written slab-tiled.
__global__ __launch_bounds__(256) void k_sage_mfma(const half_t* __restrict__ ha,
                                                   const half_t* __restrict__ hs,
                                                   const half_t* __restrict__ wl,
                                                   const half_t* __restrict__ wr,
                                                   const float* __restrict__ bias,
                                                   half_t* __restrict__ out, int n) {
  size_t np1s = (size_t)(n + 1) * 16;
  int lane = threadIdx.x & 63;
  int wid = threadIdx.x >> 6;
  int row0 = blockIdx.x * 64 + wid * 16;
  if (row0 >= n) return;
  int arow = row0 + (lane & 15);
  int arowc = arow < n ? arow : n - 1;
  int koff = (lane >> 4) << 3;
  const half8* WL = (const half8*)wl;
  const half8* WR = (const half8*)wr;
  f32x4 acc[8];
#pragma unroll
  for (int t = 0; t < 8; ++t) acc[t] = (f32x4){0.f, 0.f, 0.f, 0.f};
#pragma unroll
  for (int ks = 0; ks < 4; ++ks) {
    int col0 = ks * 32 + koff;
    size_t adr = (size_t)(col0 >> 4) * np1s + (size_t)arowc * 16 + (col0 & 15);
    half8 aD = *(const half8*)&ha[adr];
    half8 aH = *(const half8*)&hs[adr];
    int fb = ks * 8;
#pragma unroll
    for (int nt = 0; nt < 8; ++nt) {
      half8 bl = WL[(size_t)(fb + nt) * 64 + lane];
      half8 br = WR[(size_t)(fb + nt) * 64 + lane];
      acc[nt] = __builtin_amdgcn_mfma_f32_16x16x32_f16(aD, bl, acc[nt], 0, 0, 0);
      acc[nt] = __builtin_amdgcn_mfma_f32_16x16x32_f16(aH, br, acc[nt], 0, 0, 0);
    }
  }
  int rbase = row0 + ((lane >> 4) << 2);
  int cl = lane & 15;
#pragma unroll
  for (int nt = 0; nt < 8; ++nt) {
    int col = nt * 16 + cl;
    float bv = bias[col];
#pragma unroll
    for (int r = 0; r < 4; ++r) {
      int row = rbase + r;
      if (row < n) {
        float v = fmaxf(acc[nt][r] + bv, 0.f);
        out[(size_t)nt * np1s + (size_t)row * 16 + cl] = (half_t)v;   // slab nt
      }
    }
  }
}

// ---------------------------------------------------------------- fused conv2 GEMM + output projection + col partials
__global__ __launch_bounds__(256) void k_sage_out(const half_t* __restrict__ ha,
                                                  const half_t* __restrict__ hs,
                                                  const half_t* __restrict__ wl,
                                                  const half_t* __restrict__ wr,
                                                  const float* __restrict__ bias2,
                                                  const half_t* __restrict__ wout,
                                                  const float* __restrict__ bout,
                                                  float* __restrict__ out,
                                                  float* __restrict__ part, int n) {
  __shared__ half_t Hs[64][132];    // 264B row stride
  __shared__ float colsum[HID];
  size_t np1s = (size_t)(n + 1) * 16;
  int tid = threadIdx.x;
  int lane = tid & 63;
  int wid = tid >> 6;
  if (tid < HID) colsum[tid] = 0.f;
  int row0 = blockIdx.x * 64 + wid * 16;
  bool active = row0 < n;

  if (active) {
    int arow = row0 + (lane & 15);
    int arowc = arow < n ? arow : n - 1;
    int koff = (lane >> 4) << 3;
    const half8* WL = (const half8*)wl;
    const half8* WR = (const half8*)wr;
    f32x4 acc[8];
#pragma unroll
    for (int t = 0; t < 8; ++t) acc[t] = (f32x4){0.f, 0.f, 0.f, 0.f};
#pragma unroll
    for (int ks = 0; ks < 4; ++ks) {
      int col0 = ks * 32 + koff;
      size_t adr = (size_t)(col0 >> 4) * np1s + (size_t)arowc * 16 + (col0 & 15);
      half8 aD = *(const half8*)&ha[adr];
      half8 aH = *(const half8*)&hs[adr];
      int fb = ks * 8;
#pragma unroll
      for (int nt = 0; nt < 8; ++nt) {
        half8 bl = WL[(size_t)(fb + nt) * 64 + lane];
        half8 br = WR[(size_t)(fb + nt) * 64 + lane];
        acc[nt] = __builtin_amdgcn_mfma_f32_16x16x32_f16(aD, bl, acc[nt], 0, 0, 0);
        acc[nt] = __builtin_amdgcn_mfma_f32_16x16x32_f16(aH, br, acc[nt], 0, 0, 0);
      }
    }
    int rb = (lane >> 4) << 2;
    int cl = lane & 15;
#pragma unroll
    for (int nt = 0; nt < 8; ++nt) {
      int col = nt * 16 + cl;
      float bv = bias2[col];
#pragma unroll
      for (int r = 0; r < 4; ++r) {
        float v = fmaxf(acc[nt][r] + bv, 0.f);
        Hs[wid * 16 + rb + r][col] = (half_t)v;
      }
    }
  }
  __syncthreads();

  if (active) {
    int lrow = wid * 16 + (lane & 15);
    int koff = (lane >> 4) << 3;
    const half8* W8 = (const half8*)wout;
    f32x4 acc2[8];
#pragma unroll
    for (int t = 0; t < 8; ++t) acc2[t] = (f32x4){0.f, 0.f, 0.f, 0.f};
#pragma unroll
    for (int ks = 0; ks < 4; ++ks) {
      half8 aH = *(const half8*)&Hs[lrow][ks * 32 + koff];
      int fb = ks * 8;
#pragma unroll
      for (int nt = 0; nt < 8; ++nt) {
        half8 b = W8[(size_t)(fb + nt) * 64 + lane];
        acc2[nt] = __builtin_amdgcn_mfma_f32_16x16x32_f16(aH, b, acc2[nt], 0, 0, 0);
      }
    }
    int rbase = row0 + ((lane >> 4) << 2);
    int cl = lane & 15;
#pragma unroll
    for (int nt = 0; nt < 8; ++nt) {
      int col = nt * 16 + cl;
      float bv = bout[col];
      float csum = 0.f;
#pragma unroll
      for (int r = 0; r < 4; ++r) {
        int row = rbase + r;
        if (row < n) {
          float v = acc2[nt][r] + bv;
          out[(size_t)row * HID + col] = v;
          csum += v;
        }
      }
      atomicAdd(&colsum[col], csum);
    }
  }
  __syncthreads();
  if (tid < HID) part[(size_t)blockIdx.x * HID + tid] = colsum[tid];
}

// ---------------------------------------------------------------- final column reduce
__global__ __launch_bounds__(256) void k_colfinal(const float* __restrict__ part,
                                                  float* __restrict__ outmean,
                                                  int rows, float inv) {
  __shared__ float red[256];
  int t = threadIdx.x;
  int col = t & 127, half = t >> 7;
  int r0 = blockIdx.x * 256;
  float s = 0.f;
  for (int r = half; r < 256; r += 2) {
    int row = r0 + r;
    if (row < rows) s += part[(size_t)row * HID + col];
  }
  red[t] = s;
  __syncthreads();
  if (t < 128) atomicAdd(&outmean[col], (red[t] + red[t + 128]) * inv);
}

// ---------------------------------------------------------------- launch
extern "C" void kernel_launch(void* const* d_in, const int* in_sizes, int n_in,
                              void* d_out, int out_size, void* d_ws, size_t ws_size,
                              hipStream_t stream) {
  const float* pos  = (const float*)d_in[0];
  const int*   an   = (const int*)d_in[1];
  const int*   ei   = (const int*)d_in[2];
  const float* Win  = (const float*)d_in[3];
  const float* bin  = (const float*)d_in[4];
  const float* W1l  = (const float*)d_in[5];
  const float* b1   = (const float*)d_in[6];
  const float* W1r  = (const float*)d_in[7];
  const float* W2l  = (const float*)d_in[8];
  const float* b2   = (const float*)d_in[9];
  const float* W2r  = (const float*)d_in[10];
  const float* Wout = (const float*)d_in[11];
  const float* bout = (const float*)d_in[12];

  int N = in_sizes[0] / 3;
  int E = in_sizes[2] / 2;
  const int* srcl = ei;
  const int* dstl = ei + E;

  float* outmean = (float*)d_out;
  float* ns      = (float*)d_out + HID;

  char* p = (char*)d_ws;
  auto take = [&](size_t bytes) {
    char* q = p;
    p += (bytes + 255) & ~(size_t)255;
    return q;
  };
  int nbuck = (N + BK_NODES - 1) / BK_NODES;       // 196
  size_t tsz = (size_t)NSLAB * (N + 1) * 16 * 2;   // slab-tiled tensor bytes
  half_t*   H0      = (half_t*)take(tsz);
  half_t*   H1      = (half_t*)take(tsz);
  half_t*   D       = (half_t*)take(tsz);
  int*      offs    = (int*)take((size_t)N * 4);
  int*      offsE   = (int*)take((size_t)N * 4);
  int*      csr     = (int*)take((size_t)nbuck * BKCAP * 4);
  unsigned* ebuf    = (unsigned*)take((size_t)nbuck * BKCAP * 4);
  int*      bcur    = (int*)take((size_t)256 * 4);
  half_t*   pW1l    = (half_t*)take((size_t)16384 * 2);
  half_t*   pW1r    = (half_t*)take((size_t)16384 * 2);
  half_t*   pW2l    = (half_t*)take((size_t)16384 * 2);
  half_t*   pW2r    = (half_t*)take((size_t)16384 * 2);
  half_t*   pWout   = (half_t*)take((size_t)16384 * 2);
  int gSage = (N + 63) / 64;
  float*    colpart = (float*)take((size_t)gSage * HID * 4);

  int gEmbed = (int)(((size_t)N * 32 + 255) / 256);
  int gNode  = (N + 3) / 4;                        // node-blocks per slice
  int gAgg   = NSLAB * gNode;
  int gBktA  = (E + EDGES_PER_BLKA - 1) / EDGES_PER_BLKA;

  k_setup<<<gEmbed + 41, 256, 0, stream>>>(pos, an, Win, bin, H0,
                                           W1l, W1r, W2l, W2r, Wout,
                                           pW1l, pW1r, pW2l, pW2r, pWout,
                                           bcur, outmean, H1,
                                           N, gEmbed);
  k_bucketA<<<gBktA, 1024, 0, stream>>>(srcl, dstl, bcur, ebuf, E);
  k_bucketB<<<nbuck, 512, 0, stream>>>(ebuf, bcur, offs, offsE, csr, N);

  // conv1
  k_aggmean_sl<<<gAgg, 256, 0, stream>>>(H0, csr, offs, offsE, D, N, gNode);
  k_sage_mfma<<<gSage, 256, 0, stream>>>(D, H0, pW1l, pW1r, b1, H1, N);
  // conv2 + output projection (fused)
  k_aggmean_sl<<<gAgg, 256, 0, stream>>>(H1, csr, offs, offsE, D, N, gNode);
  k_sage_out<<<gSage, 256, 0, stream>>>(D, H1, pW2l, pW2r, b2, pWout, bout, ns, colpart, N);
  k_colfinal<<<(gSage + 255) / 256, 256, 0, stream>>>(colpart, outmean, gSage, 1.0f / (float)N);
}

// Round 17
// 278.248 us; speedup vs baseline: 2.8824x; 2.8824x over previous
//
#include <hip/hip_runtime.h>

#define HID 128
#define BK_SHIFT 9            // 512 nodes per bucket
#define BK_NODES 512
#define BKCAP 10240           // padded slots per bucket (mean 8192, sigma ~90)
#define EDGES_PER_BLKA 8192

typedef _Float16 half_t;
typedef __attribute__((ext_vector_type(8))) _Float16 half8;
typedef __attribute__((ext_vector_type(4))) _Float16 half4;
typedef __attribute__((ext_vector_type(4))) float f32x4;

// ---------------------------------------------------------------- fused setup: embed | packW x5 | init
__global__ __launch_bounds__(256) void k_setup(const float* __restrict__ pos,
                                               const int* __restrict__ an,
                                               const float* __restrict__ Win,
                                               const float* __restrict__ bin,
                                               half_t* __restrict__ h0,
                                               const float* __restrict__ w0,
                                               const float* __restrict__ w1,
                                               const float* __restrict__ w2,
                                               const float* __restrict__ w3,
                                               const float* __restrict__ w4,
                                               half_t* __restrict__ o0,
                                               half_t* __restrict__ o1,
                                               half_t* __restrict__ o2,
                                               half_t* __restrict__ o3,
                                               half_t* __restrict__ o4,
                                               int* __restrict__ bcur,
                                               float* __restrict__ outmean,
                                               half_t* __restrict__ h0z,
                                               half_t* __restrict__ h1z,
                                               int n, int gEmbed) {
  int bid = blockIdx.x;
  if (bid < gEmbed) {
    int t = bid * 256 + threadIdx.x;
    int i = t >> 5, cg = t & 31;
    if (i >= n) return;
    int j0 = cg << 2;
    float z  = (float)an[i] / 10.0f;
    float px = pos[3 * i + 0], py = pos[3 * i + 1], pz = pos[3 * i + 2];
    float4 ww0 = *(const float4*)&Win[0 * HID + j0];
    float4 ww1 = *(const float4*)&Win[1 * HID + j0];
    float4 ww2 = *(const float4*)&Win[2 * HID + j0];
    float4 ww3 = *(const float4*)&Win[3 * HID + j0];
    float4 b   = *(const float4*)&bin[j0];
    float4 o;
    o.x = fmaxf(fmaf(z, ww0.x, fmaf(px, ww1.x, fmaf(py, ww2.x, fmaf(pz, ww3.x, b.x)))), 0.f);
    o.y = fmaxf(fmaf(z, ww0.y, fmaf(px, ww1.y, fmaf(py, ww2.y, fmaf(pz, ww3.y, b.y)))), 0.f);
    o.z = fmaxf(fmaf(z, ww0.z, fmaf(px, ww1.z, fmaf(py, ww2.z, fmaf(pz, ww3.z, b.z)))), 0.f);
    o.w = fmaxf(fmaf(z, ww0.w, fmaf(px, ww1.w, fmaf(py, ww2.w, fmaf(pz, ww3.w, b.w)))), 0.f);
    half4 ph;
    ph.x = (half_t)o.x; ph.y = (half_t)o.y; ph.z = (half_t)o.z; ph.w = (half_t)o.w;
    *(half4*)&h0[(size_t)i * HID + j0] = ph;
  } else if (bid < gEmbed + 40) {
    int pb = bid - gEmbed;
    int m = pb >> 3;
    const float* W = (m == 0) ? w0 : (m == 1) ? w1 : (m == 2) ? w2 : (m == 3) ? w3 : w4;
    half_t* out = (m == 0) ? o0 : (m == 1) ? o1 : (m == 2) ? o2 : (m == 3) ? o3 : o4;
    int tid = (pb & 7) * 256 + threadIdx.x;   // 0..2047
    int lane = tid & 63;
    int frag = tid >> 6;                      // 0..31
    int ks = frag >> 3, nt = frag & 7;
    int k0 = ks * 32 + ((lane >> 4) << 3);
    int col = nt * 16 + (lane & 15);
    half8 v;
#pragma unroll
    for (int i = 0; i < 8; ++i) v[i] = (half_t)W[(k0 + i) * HID + col];
    *(half8*)&out[(size_t)tid * 8] = v;
  } else {
    int i = threadIdx.x;
    bcur[i] = i * BKCAP;
    if (i < HID) outmean[i] = 0.f;
    if (i < HID) h0z[i] = (half_t)0.f;
    else         h1z[i - HID] = (half_t)0.f;
  }
}

// ---------------------------------------------------------------- pass A: bin edges into padded dst-buckets
// each thread handles 8 CONTIGUOUS edges via int4 loads (32B/lane)
__global__ __launch_bounds__(1024) void k_bucketA(const int* __restrict__ src,
                                                  const int* __restrict__ dst,
                                                  int* __restrict__ bcur,
                                                  unsigned* __restrict__ ebuf,
                                                  int e) {
  __shared__ int hist[256];
  __shared__ int resv[256];
  int t = threadIdx.x;
  if (t < 256) hist[t] = 0;
  __syncthreads();
  int base = blockIdx.x * EDGES_PER_BLKA + t * 8;
  int myb[8], myr[8];
  unsigned mypk[8];
  if (base + 8 <= e) {
    int4 sa = *(const int4*)&src[base];
    int4 sb = *(const int4*)&src[base + 4];
    int4 da = *(const int4*)&dst[base];
    int4 db = *(const int4*)&dst[base + 4];
    int ss[8] = {sa.x, sa.y, sa.z, sa.w, sb.x, sb.y, sb.z, sb.w};
    int dd[8] = {da.x, da.y, da.z, da.w, db.x, db.y, db.z, db.w};
#pragma unroll
    for (int i = 0; i < 8; ++i) {
      int b = dd[i] >> BK_SHIFT;
      myb[i] = b;
      myr[i] = atomicAdd(&hist[b], 1);
      mypk[i] = ((unsigned)ss[i] << BK_SHIFT) | (unsigned)(dd[i] & (BK_NODES - 1));
    }
  } else {
#pragma unroll
    for (int i = 0; i < 8; ++i) {
      int idx = base + i;
      if (idx < e) {
        int d = dst[idx];
        int s = src[idx];
        int b = d >> BK_SHIFT;
        myb[i] = b;
        myr[i] = atomicAdd(&hist[b], 1);
        mypk[i] = ((unsigned)s << BK_SHIFT) | (unsigned)(d & (BK_NODES - 1));
      } else {
        myb[i] = -1;
      }
    }
  }
  __syncthreads();
  if (t < 256) resv[t] = (hist[t] > 0) ? atomicAdd(&bcur[t], hist[t]) : 0;
  __syncthreads();
#pragma unroll
  for (int i = 0; i < 8; ++i) {
    if (myb[i] >= 0) ebuf[resv[myb[i]] + myr[i]] = mypk[i];
  }
}

// ---------------------------------------------------------------- pass B: per bucket (512 threads): LDS hist -> scan -> offs + csr
// uint4-vectorized ebuf sweeps
__global__ __launch_bounds__(512) void k_bucketB(const unsigned* __restrict__ ebuf,
                                                 const int* __restrict__ bkend,
                                                 int* __restrict__ offs,
                                                 int* __restrict__ offsE,
                                                 int* __restrict__ csr, int n) {
  __shared__ int hist[BK_NODES];
  __shared__ int red[BK_NODES];
  int b = blockIdx.x;
  int n0 = b << BK_SHIFT;
  int t = threadIdx.x;
  int ebeg = b * BKCAP, eend = bkend[b];
  hist[t] = 0;
  __syncthreads();
  // pass 1: count local dst (uint4)
  for (int idx = ebeg + t * 4; idx < eend; idx += 2048) {
    if (idx + 4 <= eend) {
      uint4 pk = *(const uint4*)&ebuf[idx];
      atomicAdd(&hist[pk.x & (BK_NODES - 1)], 1);
      atomicAdd(&hist[pk.y & (BK_NODES - 1)], 1);
      atomicAdd(&hist[pk.z & (BK_NODES - 1)], 1);
      atomicAdd(&hist[pk.w & (BK_NODES - 1)], 1);
    } else {
      for (int k = 0; k < 4; ++k) {
        int id2 = idx + k;
        if (id2 < eend) atomicAdd(&hist[ebuf[id2] & (BK_NODES - 1)], 1);
      }
    }
  }
  __syncthreads();
  int h0 = hist[t];
  red[t] = h0;
  __syncthreads();
  for (int d = 1; d < 512; d <<= 1) {
    int u = (t >= d) ? red[t - d] : 0;
    __syncthreads();
    red[t] += u;
    __syncthreads();
  }
  int base0 = ebeg + (red[t] - h0);   // exclusive
  int g = n0 + t;
  if (g < n) { offs[g] = base0; offsE[g] = base0 + h0; }
  __syncthreads();
  hist[t] = base0;
  __syncthreads();
  // pass 2: scatter into csr (uint4 reads, ~64KB write window)
  for (int idx = ebeg + t * 4; idx < eend; idx += 2048) {
    if (idx + 4 <= eend) {
      uint4 pk = *(const uint4*)&ebuf[idx];
      csr[atomicAdd(&hist[pk.x & (BK_NODES - 1)], 1)] = (int)(pk.x >> BK_SHIFT);
      csr[atomicAdd(&hist[pk.y & (BK_NODES - 1)], 1)] = (int)(pk.y >> BK_SHIFT);
      csr[atomicAdd(&hist[pk.z & (BK_NODES - 1)], 1)] = (int)(pk.z >> BK_SHIFT);
      csr[atomicAdd(&hist[pk.w & (BK_NODES - 1)], 1)] = (int)(pk.w >> BK_SHIFT);
    } else {
      for (int k = 0; k < 4; ++k) {
        int id2 = idx + k;
        if (id2 < eend) {
          unsigned pk = ebuf[id2];
          csr[atomicAdd(&hist[pk & (BK_NODES - 1)], 1)] = (int)(pk >> BK_SHIFT);
        }
      }
    }
  }
}

// ---------------------------------------------------------------- mean aggregation, 16 lanes/edge-row, dwordx4 loads
__global__ __launch_bounds__(256) void k_aggmean_f16(const half_t* __restrict__ h,
                                                     const int* __restrict__ csr,
                                                     const int* __restrict__ offs,
                                                     const int* __restrict__ offsE,
                                                     half_t* __restrict__ out, int n) {
  int w = (blockIdx.x * 256 + threadIdx.x) >> 6;
  int lane = threadIdx.x & 63;
  if (w >= n) return;
  int cs = lane & 15, es = lane >> 4;
  int beg = offs[w], end = offsE[w];
  size_t coff = (size_t)(cs * 8);
  float acc[8];
#pragma unroll
  for (int j = 0; j < 8; ++j) acc[j] = 0.f;
  int e = beg;
  for (; e + 16 <= end; e += 16) {
    int s0 = csr[e + es];
    int s1 = csr[e + 4 + es];
    int s2 = csr[e + 8 + es];
    int s3 = csr[e + 12 + es];
    half8 v0 = *(const half8*)&h[(size_t)s0 * HID + coff];
    half8 v1 = *(const half8*)&h[(size_t)s1 * HID + coff];
    half8 v2 = *(const half8*)&h[(size_t)s2 * HID + coff];
    half8 v3 = *(const half8*)&h[(size_t)s3 * HID + coff];
#pragma unroll
    for (int j = 0; j < 8; ++j)
      acc[j] += ((float)v0[j] + (float)v1[j]) + ((float)v2[j] + (float)v3[j]);
  }
  for (; e < end; e += 4) {
    int ee = e + es;
    if (ee < end) {
      int s = csr[ee];
      half8 v = *(const half8*)&h[(size_t)s * HID + coff];
#pragma unroll
      for (int j = 0; j < 8; ++j) acc[j] += (float)v[j];
    }
  }
#pragma unroll
  for (int j = 0; j < 8; ++j) {
    acc[j] += __shfl_xor(acc[j], 16, 64);
    acc[j] += __shfl_xor(acc[j], 32, 64);
  }
  if (es == 0) {
    int c = end - beg;
    float inv = (c > 0) ? 1.0f / (float)c : 0.0f;
    half8 o;
#pragma unroll
    for (int j = 0; j < 8; ++j) o[j] = (half_t)(acc[j] * inv);
    *(half8*)&out[(size_t)w * HID + coff] = o;
  }
}

// ---------------------------------------------------------------- MFMA SAGE (conv1): out = relu(ha@Wl + hs@Wr + b), fp16
__global__ __launch_bounds__(256) void k_sage_mfma(const half_t* __restrict__ ha,
                                                   const half_t* __restrict__ hs,
                                                   const half_t* __restrict__ wl,
                                                   const half_t* __restrict__ wr,
                                                   const float* __restrict__ bias,
                                                   half_t* __restrict__ out, int n) {
  int lane = threadIdx.x & 63;
  int wid = threadIdx.x >> 6;
  int row0 = blockIdx.x * 64 + wid * 16;
  if (row0 >= n) return;
  int arow = row0 + (lane & 15);
  int arowc = arow < n ? arow : n - 1;
  size_t abase = (size_t)arowc * HID + ((lane >> 4) << 3);
  const half8* WL = (const half8*)wl;
  const half8* WR = (const half8*)wr;
  f32x4 acc[8];
#pragma unroll
  for (int t = 0; t < 8; ++t) acc[t] = (f32x4){0.f, 0.f, 0.f, 0.f};
#pragma unroll
  for (int ks = 0; ks < 4; ++ks) {
    half8 aD = *(const half8*)&ha[abase + ks * 32];
    half8 aH = *(const half8*)&hs[abase + ks * 32];
    int fb = ks * 8;
#pragma unroll
    for (int nt = 0; nt < 8; ++nt) {
      half8 bl = WL[(size_t)(fb + nt) * 64 + lane];
      half8 br = WR[(size_t)(fb + nt) * 64 + lane];
      acc[nt] = __builtin_amdgcn_mfma_f32_16x16x32_f16(aD, bl, acc[nt], 0, 0, 0);
      acc[nt] = __builtin_amdgcn_mfma_f32_16x16x32_f16(aH, br, acc[nt], 0, 0, 0);
    }
  }
  int rbase = row0 + ((lane >> 4) << 2);
  int cl = lane & 15;
#pragma unroll
  for (int nt = 0; nt < 8; ++nt) {
    int col = nt * 16 + cl;
    float bv = bias[col];
#pragma unroll
    for (int r = 0; r < 4; ++r) {
      int row = rbase + r;
      if (row < n) {
        float v = fmaxf(acc[nt][r] + bv, 0.f);
        out[(size_t)row * HID + col] = (half_t)v;
      }
    }
  }
}

// ---------------------------------------------------------------- fused conv2 GEMM + output projection + col partials
// h2 = relu(ha@W2l + hs@W2r + b2) stays in registers -> LDS -> ns = h2@Wout + bout; partial col sums
__global__ __launch_bounds__(256) void k_sage_out(const half_t* __restrict__ ha,
                                                  const half_t* __restrict__ hs,
                                                  const half_t* __restrict__ wl,
                                                  const half_t* __restrict__ wr,
                                                  const float* __restrict__ bias2,
                                                  const half_t* __restrict__ wout,
                                                  const float* __restrict__ bout,
                                                  float* __restrict__ out,
                                                  float* __restrict__ part, int n) {
  __shared__ half_t Hs[64][132];    // 264B row stride -> <=4-way bank aliasing on b128 reads
  __shared__ float colsum[HID];
  int tid = threadIdx.x;
  int lane = tid & 63;
  int wid = tid >> 6;
  if (tid < HID) colsum[tid] = 0.f;
  int row0 = blockIdx.x * 64 + wid * 16;
  bool active = row0 < n;

  // ---- phase 1: conv2 GEMM, result -> LDS stripe (per-wave exclusive)
  if (active) {
    int arow = row0 + (lane & 15);
    int arowc = arow < n ? arow : n - 1;
    size_t abase = (size_t)arowc * HID + ((lane >> 4) << 3);
    const half8* WL = (const half8*)wl;
    const half8* WR = (const half8*)wr;
    f32x4 acc[8];
#pragma unroll
    for (int t = 0; t < 8; ++t) acc[t] = (f32x4){0.f, 0.f, 0.f, 0.f};
#pragma unroll
    for (int ks = 0; ks < 4; ++ks) {
      half8 aD = *(const half8*)&ha[abase + ks * 32];
      half8 aH = *(const half8*)&hs[abase + ks * 32];
      int fb = ks * 8;
#pragma unroll
      for (int nt = 0; nt < 8; ++nt) {
        half8 bl = WL[(size_t)(fb + nt) * 64 + lane];
        half8 br = WR[(size_t)(fb + nt) * 64 + lane];
        acc[nt] = __builtin_amdgcn_mfma_f32_16x16x32_f16(aD, bl, acc[nt], 0, 0, 0);
        acc[nt] = __builtin_amdgcn_mfma_f32_16x16x32_f16(aH, br, acc[nt], 0, 0, 0);
      }
    }
    int rb = (lane >> 4) << 2;
    int cl = lane & 15;
#pragma unroll
    for (int nt = 0; nt < 8; ++nt) {
      int col = nt * 16 + cl;
      float bv = bias2[col];
#pragma unroll
      for (int r = 0; r < 4; ++r) {
        float v = fmaxf(acc[nt][r] + bv, 0.f);
        Hs[wid * 16 + rb + r][col] = (half_t)v;
      }
    }
  }
  __syncthreads();

  // ---- phase 2: ns = h2 @ Wout + bout, A from LDS
  if (active) {
    int lrow = wid * 16 + (lane & 15);
    int koff = (lane >> 4) << 3;
    const half8* W8 = (const half8*)wout;
    f32x4 acc2[8];
#pragma unroll
    for (int t = 0; t < 8; ++t) acc2[t] = (f32x4){0.f, 0.f, 0.f, 0.f};
#pragma unroll
    for (int ks = 0; ks < 4; ++ks) {
      half8 aH = *(const half8*)&Hs[lrow][ks * 32 + koff];
      int fb = ks * 8;
#pragma unroll
      for (int nt = 0; nt < 8; ++nt) {
        half8 b = W8[(size_t)(fb + nt) * 64 + lane];
        acc2[nt] = __builtin_amdgcn_mfma_f32_16x16x32_f16(aH, b, acc2[nt], 0, 0, 0);
      }
    }
    int rbase = row0 + ((lane >> 4) << 2);
    int cl = lane & 15;
#pragma unroll
    for (int nt = 0; nt < 8; ++nt) {
      int col = nt * 16 + cl;
      float bv = bout[col];
      float csum = 0.f;
#pragma unroll
      for (int r = 0; r < 4; ++r) {
        int row = rbase + r;
        if (row < n) {
          float v = acc2[nt][r] + bv;
          out[(size_t)row * HID + col] = v;
          csum += v;
        }
      }
      atomicAdd(&colsum[col], csum);
    }
  }
  __syncthreads();
  if (tid < HID) part[(size_t)blockIdx.x * HID + tid] = colsum[tid];
}

// ---------------------------------------------------------------- final column reduce
__global__ __launch_bounds__(256) void k_colfinal(const float* __restrict__ part,
                                                  float* __restrict__ outmean,
                                                  int rows, float inv) {
  __shared__ float red[256];
  int t = threadIdx.x;
  int col = t & 127, half = t >> 7;
  int r0 = blockIdx.x * 256;
  float s = 0.f;
  for (int r = half; r < 256; r += 2) {
    int row = r0 + r;
    if (row < rows) s += part[(size_t)row * HID + col];
  }
  red[t] = s;
  __syncthreads();
  if (t < 128) atomicAdd(&outmean[col], (red[t] + red[t + 128]) * inv);
}

// ---------------------------------------------------------------- launch
extern "C" void kernel_launch(void* const* d_in, const int* in_sizes, int n_in,
                              void* d_out, int out_size, void* d_ws, size_t ws_size,
                              hipStream_t stream) {
  const float* pos  = (const float*)d_in[0];
  const int*   an   = (const int*)d_in[1];
  const int*   ei   = (const int*)d_in[2];
  const float* Win  = (const float*)d_in[3];
  const float* bin  = (const float*)d_in[4];
  const float* W1l  = (const float*)d_in[5];
  const float* b1   = (const float*)d_in[6];
  const float* W1r  = (const float*)d_in[7];
  const float* W2l  = (const float*)d_in[8];
  const float* b2   = (const float*)d_in[9];
  const float* W2r  = (const float*)d_in[10];
  const float* Wout = (const float*)d_in[11];
  const float* bout = (const float*)d_in[12];

  int N = in_sizes[0] / 3;
  int E = in_sizes[2] / 2;
  const int* srcl = ei;
  const int* dstl = ei + E;

  float* outmean = (float*)d_out;
  float* ns      = (float*)d_out + HID;

  char* p = (char*)d_ws;
  auto take = [&](size_t bytes) {
    char* q = p;
    p += (bytes + 255) & ~(size_t)255;
    return q;
  };
  int nbuck = (N + BK_NODES - 1) / BK_NODES;       // 196
  half_t*   H0      = (half_t*)take((size_t)(N + 1) * HID * 2);   // +1 zero row
  half_t*   H1      = (half_t*)take((size_t)(N + 1) * HID * 2);   // +1 zero row
  half_t*   D       = (half_t*)take((size_t)N * HID * 2);
  int*      offs    = (int*)take((size_t)N * 4);
  int*      offsE   = (int*)take((size_t)N * 4);
  int*      csr     = (int*)take((size_t)nbuck * BKCAP * 4);
  unsigned* ebuf    = (unsigned*)take((size_t)nbuck * BKCAP * 4);
  int*      bcur    = (int*)take((size_t)256 * 4);
  half_t*   pW1l    = (half_t*)take((size_t)16384 * 2);
  half_t*   pW1r    = (half_t*)take((size_t)16384 * 2);
  half_t*   pW2l    = (half_t*)take((size_t)16384 * 2);
  half_t*   pW2r    = (half_t*)take((size_t)16384 * 2);
  half_t*   pWout   = (half_t*)take((size_t)16384 * 2);
  int gSage = (N + 63) / 64;
  float*    colpart = (float*)take((size_t)gSage * HID * 4);

  int gEmbed = (int)(((size_t)N * 32 + 255) / 256);
  int gWave  = (N + 3) / 4;
  int gBktA  = (E + EDGES_PER_BLKA - 1) / EDGES_PER_BLKA;

  k_setup<<<gEmbed + 41, 256, 0, stream>>>(pos, an, Win, bin, H0,
                                           W1l, W1r, W2l, W2r, Wout,
                                           pW1l, pW1r, pW2l, pW2r, pWout,
                                           bcur, outmean,
                                           &H0[(size_t)N * HID], &H1[(size_t)N * HID],
                                           N, gEmbed);
  k_bucketA<<<gBktA, 1024, 0, stream>>>(srcl, dstl, bcur, ebuf, E);
  k_bucketB<<<nbuck, 512, 0, stream>>>(ebuf, bcur, offs, offsE, csr, N);

  // conv1
  k_aggmean_f16<<<gWave, 256, 0, stream>>>(H0, csr, offs, offsE, D, N);
  k_sage_mfma<<<gSage, 256, 0, stream>>>(D, H0, pW1l, pW1r, b1, H1, N);
  // conv2 + output projection (fused)
  k_aggmean_f16<<<gWave, 256, 0, stream>>>(H1, csr, offs, offsE, D, N);
  k_sage_out<<<gSage, 256, 0, stream>>>(D, H1, pW2l, pW2r, b2, pWout, bout, ns, colpart, N);
  k_colfinal<<<(gSage + 255) / 256, 256, 0, stream>>>(colpart, outmean, gSage, 1.0f / (float)N);
}